// Round 6
// baseline (324.088 us; speedup 1.0000x reference)
//
#include <hip/hip_runtime.h>

#define BB 8
#define LLEN 896
#define DMODEL 320
#define NHEAD 10
#define DHEAD 32
#define DINNER 1280
#define ROWS (BB*LLEN)   // 7168

typedef float f32x4 __attribute__((ext_vector_type(4)));
typedef float f32x16 __attribute__((ext_vector_type(16)));
typedef __bf16 bf16x8 __attribute__((ext_vector_type(8)));
typedef short s16x8 __attribute__((ext_vector_type(8)));

__device__ __forceinline__ float bf2f(unsigned short u) {
    union { unsigned int i; float f; } x;
    x.i = ((unsigned int)u) << 16;
    return x.f;
}
__device__ __forceinline__ unsigned short f2bf(float f) {
    unsigned int u = __float_as_uint(f);
    u += 0x7FFF + ((u >> 16) & 1);   // round-to-nearest-even
    return (unsigned short)(u >> 16);
}

#define GLOAD16(g, l)                                                              \
    __builtin_amdgcn_global_load_lds(                                              \
        (const __attribute__((address_space(1))) void*)(g),                        \
        (__attribute__((address_space(3))) void*)(__attribute__((address_space(3))) char*)(l), \
        16, 0, 0)

// ---------------- weight transpose fp32 -> bf16 (dst[C][R] = src[R][C]) ----------------
__global__ __launch_bounds__(256) void transpose_bf16(const float* __restrict__ src,
                                                      unsigned short* __restrict__ dst,
                                                      int R, int C) {
    __shared__ float tile[32][33];
    int c0 = blockIdx.x * 32;
    int r0 = blockIdx.y * 32;
    int tx = threadIdx.x & 31, ty = threadIdx.x >> 5;
#pragma unroll
    for (int k = 0; k < 4; ++k) {
        int yy = ty + 8 * k;
        tile[yy][tx] = src[(size_t)(r0 + yy) * C + c0 + tx];
    }
    __syncthreads();
#pragma unroll
    for (int k = 0; k < 4; ++k) {
        int yy = ty + 8 * k;
        dst[(size_t)(c0 + yy) * R + r0 + tx] = f2bf(tile[tx][yy]);
    }
}

// ---------------- mask/bias pre-pass, m-tiled layout ----------------
// combo[((b*28 + mt)*896 + n)*32 + ml] = bf16(-g*D[b,n,m]+nm[b,n,m]) | bf16(mask[b,n,m])<<16
__global__ __launch_bounds__(256) void prepass(const float* __restrict__ D,
                                               const float* __restrict__ nm,
                                               const float* __restrict__ mk,
                                               const float* __restrict__ gamma,
                                               unsigned int* __restrict__ combo) {
    __shared__ unsigned int tile[32][33];   // [n_local][m_local]
    int mt = blockIdx.x, m0 = mt * 32;
    int n0 = blockIdx.y * 32;
    int b = blockIdx.z;
    int sn = (n0 < 128) ? 0 : (n0 < 384) ? 1 : 2;   // tiles never straddle 128/384
    int sm = (m0 < 128) ? 0 : (m0 < 384) ? 1 : 2;
    float g = gamma[sn * 4 + sm];
    int tx = threadIdx.x & 31, ty = threadIdx.x >> 5;
#pragma unroll
    for (int k = 0; k < 4; ++k) {
        int nl = ty + 8 * k;
        size_t idx = ((size_t)b * LLEN + n0 + nl) * LLEN + m0 + tx;
        float bias = -g * D[idx] + nm[idx];
        tile[nl][tx] = (unsigned int)f2bf(bias) | ((unsigned int)f2bf(mk[idx]) << 16);
    }
    __syncthreads();
#pragma unroll
    for (int k = 0; k < 4; ++k) {
        int nl = ty + 8 * k;
        combo[(((size_t)b * 28 + mt) * LLEN + n0 + nl) * 32 + tx] = tile[nl][tx];
    }
}

// ---------------- V transpose: Vt[b][h][d][m] from qkv ----------------
__global__ __launch_bounds__(256) void vt_kernel(const unsigned short* __restrict__ qkv,
                                                 unsigned short* __restrict__ Vt) {
    __shared__ unsigned short tile[32][33];   // [m_local][d]
    int mt = blockIdx.x, h = blockIdx.y, b = blockIdx.z;
    int tx = threadIdx.x & 31, ty = threadIdx.x >> 5;
#pragma unroll
    for (int k = 0; k < 4; ++k) {
        int ml = ty + 8 * k;
        tile[ml][tx] = qkv[((size_t)(b * LLEN) + mt * 32 + ml) * 960 + h * 96 + tx];
    }
    __syncthreads();
#pragma unroll
    for (int k = 0; k < 4; ++k) {
        int d = ty + 8 * k;
        Vt[(((size_t)b * NHEAD + h) * 32 + d) * LLEN + mt * 32 + tx] = tile[tx][d];
    }
}

// ---------------- LayerNorm (fp32 in, bf16 out) ----------------
__global__ __launch_bounds__(320) void ln_kernel(const float* __restrict__ x,
                                                 const float* __restrict__ g,
                                                 const float* __restrict__ bia,
                                                 unsigned short* __restrict__ y) {
    int row = blockIdx.x;
    int t = threadIdx.x;
    float v = x[(size_t)row * DMODEL + t];
    float s = v;
#pragma unroll
    for (int o = 1; o < 64; o <<= 1) s += __shfl_xor(s, o, 64);
    __shared__ float red[10];
    int w = t >> 6;
    if ((t & 63) == 0) red[w] = s;
    __syncthreads();
    float mu = (red[0] + red[1] + red[2] + red[3] + red[4]) * (1.0f / DMODEL);
    float d = v - mu;
    float s2 = d * d;
#pragma unroll
    for (int o = 1; o < 64; o <<= 1) s2 += __shfl_xor(s2, o, 64);
    if ((t & 63) == 0) red[5 + w] = s2;
    __syncthreads();
    float var = (red[5] + red[6] + red[7] + red[8] + red[9]) * (1.0f / DMODEL);
    float inv = rsqrtf(var + 1e-5f);
    y[(size_t)row * DMODEL + t] = f2bf(d * inv * g[t] + bia[t]);
}

// ---------------- bf16 MFMA GEMM: 256x64 tile, BK=64, global_load_lds ----------------
// A (MxK) @ BT(NxK)^T. 4 waves stacked in M; wave owns 64x64 = 4x4 frags of 16x16x32.
// EPI: 0 = +bias -> bf16 ; 1 = +resid(f32) -> f32 ; 2 = +bias,relu -> bf16 ; 3 = +bias+resid -> f32
template <int EPI>
__global__ __launch_bounds__(256) void gemm_bt(const unsigned short* __restrict__ A,
                                               const unsigned short* __restrict__ BT,
                                               const float* __restrict__ bias,
                                               const float* __restrict__ resid,
                                               void* __restrict__ outv,
                                               int M, int N, int K) {
    __shared__ unsigned short As[256][64];   // linear, 32 KB
    __shared__ unsigned short Bs[64][64];    // linear, 8 KB
    int tid = threadIdx.x;
    int m0 = blockIdx.x * 256;
    int n0 = blockIdx.y * 64;
    int wid = tid >> 6, l = tid & 63;
    int lr = l & 15, lh = l >> 4;
    int srow = tid >> 3;             // 0..31 (row within a 32-row stage chunk)
    int scol = (tid & 7) * 8;        // elem col within 64

    f32x4 acc[4][4];
#pragma unroll
    for (int mi = 0; mi < 4; ++mi)
#pragma unroll
        for (int ni = 0; ni < 4; ++ni) acc[mi][ni] = (f32x4){0.f, 0.f, 0.f, 0.f};

    for (int k0 = 0; k0 < K; k0 += 64) {
        __syncthreads();
#pragma unroll
        for (int i = 0; i < 8; ++i)
            GLOAD16(&A[(size_t)(m0 + i * 32 + srow) * K + k0 + scol],
                    (char*)&As[0][0] + i * 4096 + tid * 16);
#pragma unroll
        for (int i = 0; i < 2; ++i)
            GLOAD16(&BT[(size_t)(n0 + i * 32 + srow) * K + k0 + scol],
                    (char*)&Bs[0][0] + i * 4096 + tid * 16);
        __syncthreads();
#pragma unroll
        for (int kk = 0; kk < 2; ++kk) {
            bf16x8 bf[4];
#pragma unroll
            for (int ni = 0; ni < 4; ++ni)
                bf[ni] = *(const bf16x8*)&Bs[ni * 16 + lr][kk * 32 + lh * 8];
#pragma unroll
            for (int mi = 0; mi < 4; ++mi) {
                bf16x8 a = *(const bf16x8*)&As[wid * 64 + mi * 16 + lr][kk * 32 + lh * 8];
#pragma unroll
                for (int ni = 0; ni < 4; ++ni)
                    acc[mi][ni] = __builtin_amdgcn_mfma_f32_16x16x32_bf16(a, bf[ni], acc[mi][ni], 0, 0, 0);
            }
        }
    }

    unsigned short* outb = (unsigned short*)outv;
    float* outf = (float*)outv;
#pragma unroll
    for (int mi = 0; mi < 4; ++mi)
#pragma unroll
        for (int ni = 0; ni < 4; ++ni) {
            int col = n0 + ni * 16 + lr;
            float bv = (EPI != 1) ? bias[col] : 0.f;
#pragma unroll
            for (int j = 0; j < 4; ++j) {
                int row = m0 + wid * 64 + mi * 16 + lh * 4 + j;
                float v = acc[mi][ni][j];
                if (EPI == 0 || EPI == 2 || EPI == 3) v += bv;
                if (EPI == 2) v = fmaxf(v, 0.0f);
                if (EPI == 1 || EPI == 3) v += resid[(size_t)row * N + col];
                if (EPI == 0 || EPI == 2) outb[(size_t)row * N + col] = f2bf(v);
                else outf[(size_t)row * N + col] = v;
            }
        }
}

// ---------------- MFMA attention ----------------
// Block = (b, 32-row n-tile), 640 threads = 10 waves, wave = head (10-wave co-residency
// is load-hiding critical: R4's 5-wave split regressed 59->72us).
// Swapped QK^T via 2x mfma_f32_32x32x16_bf16; no online max (scores bounded);
// P->A-frag via bf16 pack + shfl_xor(32); PV with Vt (contiguous B-frags).
__global__ __launch_bounds__(640) void attn_mfma(const unsigned short* __restrict__ qkv,
                                                 const unsigned short* __restrict__ Vt,
                                                 const unsigned int* __restrict__ combo,
                                                 unsigned short* __restrict__ attn) {
    int tid = threadIdx.x;
    int h = tid >> 6;           // head = wave
    int l = tid & 63;
    int c = l & 31;
    int hi = l >> 5;
    int nt = blockIdx.x % 28;
    int b = blockIdx.x / 28;
    int n0 = nt * 32;

    // Q as B-fragment: lane holds Q[n0+c][kk*16 + hi*8 + e]
    size_t qbase = ((size_t)(b * LLEN + n0 + c)) * 960 + h * 96 + 32 + hi * 8;
    bf16x8 qB0 = *(const bf16x8*)&qkv[qbase];
    bf16x8 qB1 = *(const bf16x8*)&qkv[qbase + 16];

    f32x16 oacc = {0.f,0.f,0.f,0.f,0.f,0.f,0.f,0.f,0.f,0.f,0.f,0.f,0.f,0.f,0.f,0.f};
    float lsum = 0.f;

    const unsigned int* cbase = combo + ((size_t)b * 28 * LLEN + n0 + c) * 32;  // + mt*896*32
    size_t kbase = (size_t)b * LLEN * 960 + h * 96 + 64 + hi * 8;               // + m*960
    const unsigned short* vrow = Vt + (((size_t)b * NHEAD + h) * 32 + c) * LLEN; // + m

    for (int mt = 0; mt < 28; ++mt) {
        // K as A-fragment: m = mt*32 + c, d = kk*16 + hi*8 + e
        size_t krow = kbase + (size_t)(mt * 32 + c) * 960;
        bf16x8 kA0 = *(const bf16x8*)&qkv[krow];
        bf16x8 kA1 = *(const bf16x8*)&qkv[krow + 16];
        f32x16 sacc = {0.f,0.f,0.f,0.f,0.f,0.f,0.f,0.f,0.f,0.f,0.f,0.f,0.f,0.f,0.f,0.f};
        sacc = __builtin_amdgcn_mfma_f32_32x32x16_bf16(kA0, qB0, sacc, 0, 0, 0);
        sacc = __builtin_amdgcn_mfma_f32_32x32x16_bf16(kA1, qB1, sacc, 0, 0, 0);

        // combo: 4x int4, chunk g covers m_loc = 8g + 4hi + (0..3)
        const unsigned int* cp = cbase + (size_t)mt * (LLEN * 32);
        int4 x4[4];
#pragma unroll
        for (int g = 0; g < 4; ++g) x4[g] = *(const int4*)&cp[8 * g + 4 * hi];

        // p[r]: n = c, m_loc = (r&3) + 8*(r>>2) + 4*hi
        float p[16];
#pragma unroll
        for (int r = 0; r < 16; ++r) {
            unsigned int cm = ((const unsigned int*)x4)[(r >> 2) * 4 + (r & 3)];
            float bias = bf2f((unsigned short)(cm & 0xffffu));
            float mk = bf2f((unsigned short)(cm >> 16));
            float s = fmaf(sacc[r], 0.17677669529663687f, bias);   // 1/sqrt(32)
            float e = __expf(s);
            lsum += e;
            p[r] = e * mk;
        }

        // pack pairs (consecutive m) and exchange halves
        unsigned int u[8], x[8];
#pragma unroll
        for (int j = 0; j < 8; ++j) {
            union { __bf16 h2[2]; unsigned int w; } pk;
            pk.h2[0] = (__bf16)p[2 * j];
            pk.h2[1] = (__bf16)p[2 * j + 1];
            u[j] = pk.w;
            x[j] = (unsigned int)__shfl_xor((int)u[j], 32, 64);
        }
        union { unsigned int w[4]; bf16x8 v; } a1, a2;
        if (hi == 0) {
            a1.w[0] = u[0]; a1.w[1] = u[1]; a1.w[2] = x[0]; a1.w[3] = x[1];
            a2.w[0] = u[4]; a2.w[1] = u[5]; a2.w[2] = x[4]; a2.w[3] = x[5];
        } else {
            a1.w[0] = x[2]; a1.w[1] = x[3]; a1.w[2] = u[2]; a1.w[3] = u[3];
            a2.w[0] = x[6]; a2.w[1] = x[7]; a2.w[2] = u[6]; a2.w[3] = u[7];
        }

        // V as B-fragment from Vt: d = c, m_loc = hi*8 + e (+16 for 2nd)
        bf16x8 v1 = *(const bf16x8*)&vrow[mt * 32 + hi * 8];
        bf16x8 v2 = *(const bf16x8*)&vrow[mt * 32 + 16 + hi * 8];
        oacc = __builtin_amdgcn_mfma_f32_32x32x16_bf16(a1.v, v1, oacc, 0, 0, 0);
        oacc = __builtin_amdgcn_mfma_f32_32x32x16_bf16(a2.v, v2, oacc, 0, 0, 0);
    }

    lsum += __shfl_xor(lsum, 32, 64);
    float invs = 1.0f / lsum;     // lane c holds inv for column n=c
#pragma unroll
    for (int r = 0; r < 16; ++r) {
        int n = (r & 3) + 8 * (r >> 2) + 4 * hi;
        float o = oacc[r] * __shfl(invs, n, 64);
        o = (o >= 0.f) ? o : 0.01f * o;   // leaky_relu(0.01)
        attn[((size_t)(b * LLEN + n0 + n)) * DMODEL + h * DHEAD + c] = f2bf(o);
    }
}

// ---------------- launch ----------------
extern "C" void kernel_launch(void* const* d_in, const int* in_sizes, int n_in,
                              void* d_out, int out_size, void* d_ws, size_t ws_size,
                              hipStream_t stream) {
    const float* Z     = (const float*)d_in[0];
    const float* Dm    = (const float*)d_in[1];
    const float* nmask = (const float*)d_in[2];
    const float* mask  = (const float*)d_in[3];
    const float* gamma = (const float*)d_in[4];
    const float* w_qkv = (const float*)d_in[5];
    const float* b_qkv = (const float*)d_in[6];
    const float* w_o   = (const float*)d_in[7];
    const float* ln1g  = (const float*)d_in[8];
    const float* ln1b  = (const float*)d_in[9];
    const float* ln2g  = (const float*)d_in[10];
    const float* ln2b  = (const float*)d_in[11];
    const float* w1    = (const float*)d_in[12];
    const float* b1    = (const float*)d_in[13];
    const float* w2    = (const float*)d_in[14];
    const float* b2    = (const float*)d_in[15];

    char* ws = (char*)d_ws;
    unsigned short* Zn    = (unsigned short*)(ws + 0);         // 7168x320 bf16
    unsigned short* qkv   = (unsigned short*)(ws + 4587520);   // 7168x960 bf16
    unsigned short* attn  = (unsigned short*)(ws + 18350080);  // 7168x320 bf16
    float*          Zres  = (float*)(ws + 22937600);           // 7168x320 f32
    unsigned short* Zn2   = (unsigned short*)(ws + 32112640);  // 7168x320 bf16
    unsigned short* Hbuf  = (unsigned short*)(ws + 36700160);  // 7168x1280 bf16
    unsigned short* wqkvT = (unsigned short*)(ws + 55050240);  // 960x320 bf16
    unsigned short* woT   = (unsigned short*)(ws + 55664640);  // 320x320 bf16
    unsigned short* w1T   = (unsigned short*)(ws + 55869440);  // 1280x320 bf16
    unsigned short* w2T   = (unsigned short*)(ws + 56688640);  // 320x1280 bf16
    unsigned int*   combo = (unsigned int*)(ws + 57507840);    // 8x28x896x32 u32 (25.7MB)
    unsigned short* Vtb   = (unsigned short*)(ws + 83197952);  // 8x10x32x896 bf16 (4.6MB)

    // weight prep
    transpose_bf16<<<dim3(960 / 32, 320 / 32), 256, 0, stream>>>(w_qkv, wqkvT, 320, 960);
    transpose_bf16<<<dim3(320 / 32, 320 / 32), 256, 0, stream>>>(w_o, woT, 320, 320);
    transpose_bf16<<<dim3(1280 / 32, 320 / 32), 256, 0, stream>>>(w1, w1T, 320, 1280);
    transpose_bf16<<<dim3(320 / 32, 1280 / 32), 256, 0, stream>>>(w2, w2T, 1280, 320);

    // mask/bias pre-pass (head-independent, read once)
    prepass<<<dim3(28, 28, 8), 256, 0, stream>>>(Dm, nmask, mask, gamma, combo);

    // LN1
    ln_kernel<<<ROWS, 320, 0, stream>>>(Z, ln1g, ln1b, Zn);

    // QKV GEMM: Zn(7168x320) @ w_qkv(320x960) + b_qkv -> qkv bf16
    gemm_bt<0><<<dim3(ROWS / 256, 960 / 64), 256, 0, stream>>>(Zn, wqkvT, b_qkv, nullptr,
                                                               (void*)qkv, ROWS, 960, 320);

    // V transpose for PV B-fragments
    vt_kernel<<<dim3(28, NHEAD, BB), 256, 0, stream>>>(qkv, Vtb);

    // MFMA attention -> leaky_relu -> attn bf16
    attn_mfma<<<BB * 28, 640, 0, stream>>>(qkv, Vtb, combo, attn);

    // W_O GEMM + residual Z -> Zres f32
    gemm_bt<1><<<dim3(ROWS / 256, 320 / 64), 256, 0, stream>>>(attn, woT, nullptr, Z,
                                                               (void*)Zres, ROWS, 320, 320);

    // LN2
    ln_kernel<<<ROWS, 320, 0, stream>>>(Zres, ln2g, ln2b, Zn2);

    // FFN1: Zn2 @ w1 + b1, relu -> H bf16
    gemm_bt<2><<<dim3(ROWS / 256, 1280 / 64), 256, 0, stream>>>(Zn2, w1T, b1, nullptr,
                                                                (void*)Hbuf, ROWS, 1280, 320);

    // FFN2: H @ w2 + b2 + Zres -> out f32
    gemm_bt<3><<<dim3(ROWS / 256, 320 / 64), 256, 0, stream>>>(Hbuf, w2T, b2, Zres,
                                                               d_out, ROWS, 320, 1280);
}

// Round 7
// 303.008 us; speedup vs baseline: 1.0696x; 1.0696x over previous
//
#include <hip/hip_runtime.h>

#define BB 8
#define LLEN 896
#define DMODEL 320
#define NHEAD 10
#define DHEAD 32
#define DINNER 1280
#define ROWS (BB*LLEN)   // 7168

typedef float f32x4 __attribute__((ext_vector_type(4)));
typedef float f32x16 __attribute__((ext_vector_type(16)));
typedef __bf16 bf16x8 __attribute__((ext_vector_type(8)));

__device__ __forceinline__ float bf2f(unsigned short u) {
    union { unsigned int i; float f; } x;
    x.i = ((unsigned int)u) << 16;
    return x.f;
}
__device__ __forceinline__ unsigned short f2bf(float f) {
    unsigned int u = __float_as_uint(f);
    u += 0x7FFF + ((u >> 16) & 1);   // round-to-nearest-even
    return (unsigned short)(u >> 16);
}

#define GLOAD16(g, l)                                                              \
    __builtin_amdgcn_global_load_lds(                                              \
        (const __attribute__((address_space(1))) void*)(g),                        \
        (__attribute__((address_space(3))) void*)(__attribute__((address_space(3))) char*)(l), \
        16, 0, 0)

// ---------------- weight transpose fp32 -> bf16 (dst[C][R] = src[R][C]) ----------------
__global__ __launch_bounds__(256) void transpose_bf16(const float* __restrict__ src,
                                                      unsigned short* __restrict__ dst,
                                                      int R, int C) {
    __shared__ float tile[32][33];
    int c0 = blockIdx.x * 32;
    int r0 = blockIdx.y * 32;
    int tx = threadIdx.x & 31, ty = threadIdx.x >> 5;
#pragma unroll
    for (int k = 0; k < 4; ++k) {
        int yy = ty + 8 * k;
        tile[yy][tx] = src[(size_t)(r0 + yy) * C + c0 + tx];
    }
    __syncthreads();
#pragma unroll
    for (int k = 0; k < 4; ++k) {
        int yy = ty + 8 * k;
        dst[(size_t)(c0 + yy) * R + r0 + tx] = f2bf(tile[tx][yy]);
    }
}

// ---------------- mask/bias pre-pass, m-tiled layout ----------------
// combo[((b*28 + mt)*896 + n)*32 + ml] = bf16(-g*D[b,n,m]+nm[b,n,m]) | bf16(mask[b,n,m])<<16
__global__ __launch_bounds__(256) void prepass(const float* __restrict__ D,
                                               const float* __restrict__ nm,
                                               const float* __restrict__ mk,
                                               const float* __restrict__ gamma,
                                               unsigned int* __restrict__ combo) {
    __shared__ unsigned int tile[32][33];   // [n_local][m_local]
    int mt = blockIdx.x, m0 = mt * 32;
    int n0 = blockIdx.y * 32;
    int b = blockIdx.z;
    int sn = (n0 < 128) ? 0 : (n0 < 384) ? 1 : 2;   // tiles never straddle 128/384
    int sm = (m0 < 128) ? 0 : (m0 < 384) ? 1 : 2;
    float g = gamma[sn * 4 + sm];
    int tx = threadIdx.x & 31, ty = threadIdx.x >> 5;
#pragma unroll
    for (int k = 0; k < 4; ++k) {
        int nl = ty + 8 * k;
        size_t idx = ((size_t)b * LLEN + n0 + nl) * LLEN + m0 + tx;
        float bias = -g * D[idx] + nm[idx];
        tile[nl][tx] = (unsigned int)f2bf(bias) | ((unsigned int)f2bf(mk[idx]) << 16);
    }
    __syncthreads();
#pragma unroll
    for (int k = 0; k < 4; ++k) {
        int nl = ty + 8 * k;
        combo[(((size_t)b * 28 + mt) * LLEN + n0 + nl) * 32 + tx] = tile[nl][tx];
    }
}

// ---------------- V transpose: Vt[b][h][d][m] from qkv ----------------
__global__ __launch_bounds__(256) void vt_kernel(const unsigned short* __restrict__ qkv,
                                                 unsigned short* __restrict__ Vt) {
    __shared__ unsigned short tile[32][33];   // [m_local][d]
    int mt = blockIdx.x, h = blockIdx.y, b = blockIdx.z;
    int tx = threadIdx.x & 31, ty = threadIdx.x >> 5;
#pragma unroll
    for (int k = 0; k < 4; ++k) {
        int ml = ty + 8 * k;
        tile[ml][tx] = qkv[((size_t)(b * LLEN) + mt * 32 + ml) * 960 + h * 96 + tx];
    }
    __syncthreads();
#pragma unroll
    for (int k = 0; k < 4; ++k) {
        int d = ty + 8 * k;
        Vt[(((size_t)b * NHEAD + h) * 32 + d) * LLEN + mt * 32 + tx] = tile[tx][d];
    }
}

// ---------------- LayerNorm (fp32 in, bf16 out) ----------------
__global__ __launch_bounds__(320) void ln_kernel(const float* __restrict__ x,
                                                 const float* __restrict__ g,
                                                 const float* __restrict__ bia,
                                                 unsigned short* __restrict__ y) {
    int row = blockIdx.x;
    int t = threadIdx.x;
    float v = x[(size_t)row * DMODEL + t];
    float s = v;
#pragma unroll
    for (int o = 1; o < 64; o <<= 1) s += __shfl_xor(s, o, 64);
    __shared__ float red[10];
    int w = t >> 6;
    if ((t & 63) == 0) red[w] = s;
    __syncthreads();
    float mu = (red[0] + red[1] + red[2] + red[3] + red[4]) * (1.0f / DMODEL);
    float d = v - mu;
    float s2 = d * d;
#pragma unroll
    for (int o = 1; o < 64; o <<= 1) s2 += __shfl_xor(s2, o, 64);
    if ((t & 63) == 0) red[5 + w] = s2;
    __syncthreads();
    float var = (red[5] + red[6] + red[7] + red[8] + red[9]) * (1.0f / DMODEL);
    float inv = rsqrtf(var + 1e-5f);
    y[(size_t)row * DMODEL + t] = f2bf(d * inv * g[t] + bia[t]);
}

// ---------------- bf16 MFMA GEMM: 128x64 tile, BK=64, global_load_lds + XOR swizzle ----
// LDS rows are 128B (64 bf16) => naive frag reads are 16-way bank conflicts.
// Fix (rule #21): linear LDS dest, inverse-swizzled GLOBAL source (lane loads chunk
// (tid&7)^(row&7)), swizzled read (chunk g at row r lives at slot g^(r&7)).
// EPI: 0 = +bias -> bf16 ; 1 = +resid(f32) -> f32 ; 2 = +bias,relu -> bf16 ; 3 = +bias+resid -> f32
template <int EPI>
__global__ __launch_bounds__(256) void gemm_bt(const unsigned short* __restrict__ A,
                                               const unsigned short* __restrict__ BT,
                                               const float* __restrict__ bias,
                                               const float* __restrict__ resid,
                                               void* __restrict__ outv,
                                               int M, int N, int K) {
    __shared__ unsigned short As[128][64];   // linear, 16 KB
    __shared__ unsigned short Bs[64][64];    // linear, 8 KB
    int tid = threadIdx.x;
    int m0 = blockIdx.x * 128;
    int n0 = blockIdx.y * 64;
    int wid = tid >> 6, l = tid & 63;
    int wr = wid >> 1, wc = wid & 1;
    int lr = l & 15, lh = l >> 4;
    int srow = tid >> 3;                    // 0..31 within a 32-row stage chunk
    int sslot = (tid & 7) ^ (srow & 7);     // inverse-swizzled source chunk

    f32x4 acc[4][2];
#pragma unroll
    for (int mi = 0; mi < 4; ++mi)
#pragma unroll
        for (int ni = 0; ni < 2; ++ni) acc[mi][ni] = (f32x4){0.f, 0.f, 0.f, 0.f};

    for (int k0 = 0; k0 < K; k0 += 64) {
        __syncthreads();
#pragma unroll
        for (int i = 0; i < 4; ++i)
            GLOAD16(&A[(size_t)(m0 + i * 32 + srow) * K + k0 + sslot * 8],
                    (char*)&As[0][0] + i * 4096 + tid * 16);
#pragma unroll
        for (int i = 0; i < 2; ++i)
            GLOAD16(&BT[(size_t)(n0 + i * 32 + srow) * K + k0 + sslot * 8],
                    (char*)&Bs[0][0] + i * 4096 + tid * 16);
        __syncthreads();
#pragma unroll
        for (int kk = 0; kk < 2; ++kk) {
            int gch = kk * 4 + lh;          // global k-chunk this frag needs
            int sl = gch ^ (lr & 7);        // swizzled LDS slot (row&7 == lr&7)
            bf16x8 b0 = *(const bf16x8*)&Bs[wc * 32 + lr][sl * 8];
            bf16x8 b1 = *(const bf16x8*)&Bs[wc * 32 + 16 + lr][sl * 8];
#pragma unroll
            for (int mi = 0; mi < 4; ++mi) {
                bf16x8 a = *(const bf16x8*)&As[wr * 64 + mi * 16 + lr][sl * 8];
                acc[mi][0] = __builtin_amdgcn_mfma_f32_16x16x32_bf16(a, b0, acc[mi][0], 0, 0, 0);
                acc[mi][1] = __builtin_amdgcn_mfma_f32_16x16x32_bf16(a, b1, acc[mi][1], 0, 0, 0);
            }
        }
    }

    unsigned short* outb = (unsigned short*)outv;
    float* outf = (float*)outv;
#pragma unroll
    for (int mi = 0; mi < 4; ++mi)
#pragma unroll
        for (int ni = 0; ni < 2; ++ni) {
            int col = n0 + wc * 32 + ni * 16 + lr;
            float bv = (EPI != 1) ? bias[col] : 0.f;
#pragma unroll
            for (int j = 0; j < 4; ++j) {
                int row = m0 + wr * 64 + mi * 16 + lh * 4 + j;
                float v = acc[mi][ni][j];
                if (EPI == 0 || EPI == 2 || EPI == 3) v += bv;
                if (EPI == 2) v = fmaxf(v, 0.0f);
                if (EPI == 1 || EPI == 3) v += resid[(size_t)row * N + col];
                if (EPI == 0 || EPI == 2) outb[(size_t)row * N + col] = f2bf(v);
                else outf[(size_t)row * N + col] = v;
            }
        }
}

// ---------------- MFMA attention, 2-deep register prefetch ----------------
// Block = (b, 32-row n-tile, head-half), 320 threads = 5 waves, wave = head.
// R6 falsified the co-residency theory (10-wave == 5-wave == 72.8us); the limiter is
// per-wave load latency (8 VMEM insts/tile, no overlap). Fix: prefetch tile mt+1's
// K/V/combo into a second register set while computing tile mt (T14, static 2-state).
__global__ __launch_bounds__(320) void attn_mfma(const unsigned short* __restrict__ qkv,
                                                 const unsigned short* __restrict__ Vt,
                                                 const unsigned int* __restrict__ combo,
                                                 unsigned short* __restrict__ attn) {
    int tid = threadIdx.x;
    int h = blockIdx.y * 5 + (tid >> 6);
    int l = tid & 63;
    int c = l & 31;
    int hi = l >> 5;
    int nt = blockIdx.x % 28;
    int b = blockIdx.x / 28;
    int n0 = nt * 32;

    size_t qbase = ((size_t)(b * LLEN + n0 + c)) * 960 + h * 96 + 32 + hi * 8;
    bf16x8 qB0 = *(const bf16x8*)&qkv[qbase];
    bf16x8 qB1 = *(const bf16x8*)&qkv[qbase + 16];

    f32x16 oacc = {0.f,0.f,0.f,0.f,0.f,0.f,0.f,0.f,0.f,0.f,0.f,0.f,0.f,0.f,0.f,0.f};
    float lsum = 0.f;

    const unsigned int* cbase = combo + ((size_t)b * 28 * LLEN + n0 + c) * 32;   // + mt*896*32
    size_t kbase = (size_t)b * LLEN * 960 + h * 96 + 64 + hi * 8;                // + m*960
    const unsigned short* vrow = Vt + (((size_t)b * NHEAD + h) * 32 + c) * LLEN; // + m

#define ALOAD(mt, K0, K1, V1_, V2_, X4)                                     \
    {                                                                       \
        size_t krow = kbase + (size_t)((mt) * 32 + c) * 960;                \
        K0 = *(const bf16x8*)&qkv[krow];                                    \
        K1 = *(const bf16x8*)&qkv[krow + 16];                               \
        V1_ = *(const bf16x8*)&vrow[(mt) * 32 + hi * 8];                    \
        V2_ = *(const bf16x8*)&vrow[(mt) * 32 + 16 + hi * 8];               \
        const unsigned int* cp = cbase + (size_t)(mt) * (LLEN * 32);        \
        X4[0] = *(const int4*)&cp[4 * hi];                                  \
        X4[1] = *(const int4*)&cp[8 + 4 * hi];                              \
        X4[2] = *(const int4*)&cp[16 + 4 * hi];                             \
        X4[3] = *(const int4*)&cp[24 + 4 * hi];                             \
    }

#define ACOMPUTE(K0, K1, V1_, V2_, X4)                                                \
    {                                                                                 \
        f32x16 sacc = {0.f,0.f,0.f,0.f,0.f,0.f,0.f,0.f,0.f,0.f,0.f,0.f,0.f,0.f,0.f,0.f}; \
        sacc = __builtin_amdgcn_mfma_f32_32x32x16_bf16(K0, qB0, sacc, 0, 0, 0);       \
        sacc = __builtin_amdgcn_mfma_f32_32x32x16_bf16(K1, qB1, sacc, 0, 0, 0);       \
        float p[16];                                                                  \
        _Pragma("unroll")                                                             \
        for (int r = 0; r < 16; ++r) {                                                \
            unsigned int cm = ((const unsigned int*)X4)[r];                           \
            float bias = bf2f((unsigned short)(cm & 0xffffu));                        \
            float mk = bf2f((unsigned short)(cm >> 16));                              \
            float s = fmaf(sacc[r], 0.17677669529663687f, bias);                      \
            float e = __expf(s);                                                      \
            lsum += e;                                                                \
            p[r] = e * mk;                                                            \
        }                                                                             \
        unsigned int u[8], x[8];                                                      \
        _Pragma("unroll")                                                             \
        for (int j = 0; j < 8; ++j) {                                                 \
            union { __bf16 h2[2]; unsigned int w; } pk;                               \
            pk.h2[0] = (__bf16)p[2 * j];                                              \
            pk.h2[1] = (__bf16)p[2 * j + 1];                                          \
            u[j] = pk.w;                                                              \
            x[j] = (unsigned int)__shfl_xor((int)u[j], 32, 64);                       \
        }                                                                             \
        union { unsigned int w[4]; bf16x8 v; } a1, a2;                                \
        if (hi == 0) {                                                                \
            a1.w[0] = u[0]; a1.w[1] = u[1]; a1.w[2] = x[0]; a1.w[3] = x[1];           \
            a2.w[0] = u[4]; a2.w[1] = u[5]; a2.w[2] = x[4]; a2.w[3] = x[5];           \
        } else {                                                                      \
            a1.w[0] = x[2]; a1.w[1] = x[3]; a1.w[2] = u[2]; a1.w[3] = u[3];           \
            a2.w[0] = x[6]; a2.w[1] = x[7]; a2.w[2] = u[6]; a2.w[3] = u[7];           \
        }                                                                             \
        oacc = __builtin_amdgcn_mfma_f32_32x32x16_bf16(a1.v, V1_, oacc, 0, 0, 0);     \
        oacc = __builtin_amdgcn_mfma_f32_32x32x16_bf16(a2.v, V2_, oacc, 0, 0, 0);     \
    }

    bf16x8 k0A, k1A, v1A, v2A; int4 xA[4];
    bf16x8 k0B, k1B, v1B, v2B; int4 xB[4];
    ALOAD(0, k0A, k1A, v1A, v2A, xA);
#pragma unroll 1
    for (int mt = 0; mt < 28; mt += 2) {
        ALOAD(mt + 1, k0B, k1B, v1B, v2B, xB);
        ACOMPUTE(k0A, k1A, v1A, v2A, xA);
        int nx = (mt + 2 < 28) ? mt + 2 : 0;   // dummy-reload tile 0 on last iter
        ALOAD(nx, k0A, k1A, v1A, v2A, xA);
        ACOMPUTE(k0B, k1B, v1B, v2B, xB);
    }

    lsum += __shfl_xor(lsum, 32, 64);
    float invs = 1.0f / lsum;     // lane c holds inv for column n=c
#pragma unroll
    for (int r = 0; r < 16; ++r) {
        int n = (r & 3) + 8 * (r >> 2) + 4 * hi;
        float o = oacc[r] * __shfl(invs, n, 64);
        o = (o >= 0.f) ? o : 0.01f * o;   // leaky_relu(0.01)
        attn[((size_t)(b * LLEN + n0 + n)) * DMODEL + h * DHEAD + c] = f2bf(o);
    }
#undef ALOAD
#undef ACOMPUTE
}

// ---------------- launch ----------------
extern "C" void kernel_launch(void* const* d_in, const int* in_sizes, int n_in,
                              void* d_out, int out_size, void* d_ws, size_t ws_size,
                              hipStream_t stream) {
    const float* Z     = (const float*)d_in[0];
    const float* Dm    = (const float*)d_in[1];
    const float* nmask = (const float*)d_in[2];
    const float* mask  = (const float*)d_in[3];
    const float* gamma = (const float*)d_in[4];
    const float* w_qkv = (const float*)d_in[5];
    const float* b_qkv = (const float*)d_in[6];
    const float* w_o   = (const float*)d_in[7];
    const float* ln1g  = (const float*)d_in[8];
    const float* ln1b  = (const float*)d_in[9];
    const float* ln2g  = (const float*)d_in[10];
    const float* ln2b  = (const float*)d_in[11];
    const float* w1    = (const float*)d_in[12];
    const float* b1    = (const float*)d_in[13];
    const float* w2    = (const float*)d_in[14];
    const float* b2    = (const float*)d_in[15];

    char* ws = (char*)d_ws;
    unsigned short* Zn    = (unsigned short*)(ws + 0);         // 7168x320 bf16
    unsigned short* qkv   = (unsigned short*)(ws + 4587520);   // 7168x960 bf16
    unsigned short* attn  = (unsigned short*)(ws + 18350080);  // 7168x320 bf16
    float*          Zres  = (float*)(ws + 22937600);           // 7168x320 f32
    unsigned short* Zn2   = (unsigned short*)(ws + 32112640);  // 7168x320 bf16
    unsigned short* Hbuf  = (unsigned short*)(ws + 36700160);  // 7168x1280 bf16
    unsigned short* wqkvT = (unsigned short*)(ws + 55050240);  // 960x320 bf16
    unsigned short* woT   = (unsigned short*)(ws + 55664640);  // 320x320 bf16
    unsigned short* w1T   = (unsigned short*)(ws + 55869440);  // 1280x320 bf16
    unsigned short* w2T   = (unsigned short*)(ws + 56688640);  // 320x1280 bf16
    unsigned int*   combo = (unsigned int*)(ws + 57507840);    // 8x28x896x32 u32 (25.7MB)
    unsigned short* Vtb   = (unsigned short*)(ws + 83197952);  // 8x10x32x896 bf16 (4.6MB)

    // weight prep
    transpose_bf16<<<dim3(960 / 32, 320 / 32), 256, 0, stream>>>(w_qkv, wqkvT, 320, 960);
    transpose_bf16<<<dim3(320 / 32, 320 / 32), 256, 0, stream>>>(w_o, woT, 320, 320);
    transpose_bf16<<<dim3(1280 / 32, 320 / 32), 256, 0, stream>>>(w1, w1T, 320, 1280);
    transpose_bf16<<<dim3(320 / 32, 1280 / 32), 256, 0, stream>>>(w2, w2T, 1280, 320);

    // mask/bias pre-pass (head-independent, read once)
    prepass<<<dim3(28, 28, 8), 256, 0, stream>>>(Dm, nmask, mask, gamma, combo);

    // LN1
    ln_kernel<<<ROWS, 320, 0, stream>>>(Z, ln1g, ln1b, Zn);

    // QKV GEMM: Zn(7168x320) @ w_qkv(320x960) + b_qkv -> qkv bf16
    gemm_bt<0><<<dim3(ROWS / 128, 960 / 64), 256, 0, stream>>>(Zn, wqkvT, b_qkv, nullptr,
                                                               (void*)qkv, ROWS, 960, 320);

    // V transpose for PV B-fragments
    vt_kernel<<<dim3(28, NHEAD, BB), 256, 0, stream>>>(qkv, Vtb);

    // MFMA attention -> leaky_relu -> attn bf16
    attn_mfma<<<dim3(BB * 28, 2), 320, 0, stream>>>(qkv, Vtb, combo, attn);

    // W_O GEMM + residual Z -> Zres f32
    gemm_bt<1><<<dim3(ROWS / 128, 320 / 64), 256, 0, stream>>>(attn, woT, nullptr, Z,
                                                               (void*)Zres, ROWS, 320, 320);

    // LN2
    ln_kernel<<<ROWS, 320, 0, stream>>>(Zres, ln2g, ln2b, Zn2);

    // FFN1: Zn2 @ w1 + b1, relu -> H bf16
    gemm_bt<2><<<dim3(ROWS / 128, 1280 / 64), 256, 0, stream>>>(Zn2, w1T, b1, nullptr,
                                                                (void*)Hbuf, ROWS, 1280, 320);

    // FFN2: H @ w2 + b2 + Zres -> out f32
    gemm_bt<3><<<dim3(ROWS / 128, 320 / 64), 256, 0, stream>>>(Hbuf, w2T, b2, Zres,
                                                               d_out, ROWS, 320, 1280);
}